// Round 5
// baseline (1055.564 us; speedup 1.0000x reference)
//
#include <hip/hip_runtime.h>
#include <math.h>

#define N_TEAMS 100000
#define N_EDGES 1600000
#define BATCH   16384
#define DIM     64
#define SLOPE   0.01f
#define NPAD    100352  // 98 * 1024

__device__ __forceinline__ float leaky(float v) { return v > 0.f ? v : SLOPE * v; }

__device__ __forceinline__ float bf2f(unsigned short u) {
    return __uint_as_float(((unsigned)u) << 16);
}
__device__ __forceinline__ unsigned short f2bf(float f) {
    unsigned b = __float_as_uint(f);
    unsigned r = b + 0x7FFFu + ((b >> 16) & 1u);  // RNE
    return (unsigned short)(r >> 16);
}
__device__ __forceinline__ float2 bf2x2(unsigned u) {
    float2 r;
    r.x = __uint_as_float(u << 16);
    r.y = __uint_as_float(u & 0xFFFF0000u);
    return r;
}

// ---- setup ---------------------------------------------------------------

__global__ void k_zero(int* __restrict__ cnt, int n) {
    int i = blockIdx.x * blockDim.x + threadIdx.x;
    if (i < n) cnt[i] = 0;
}

__global__ void k_cnt(const int* __restrict__ dst, int* __restrict__ cnt, int E) {
    int e = blockIdx.x * blockDim.x + threadIdx.x;
    if (e < E) atomicAdd(&cnt[__builtin_nontemporal_load(dst + e)], 1);
}

// ---- 2-level exclusive scan of cnt -> row_start (+ fill copy) ------------

__global__ __launch_bounds__(1024) void k_scan1(const int* __restrict__ cnt,
                                                int* __restrict__ excl,
                                                int* __restrict__ partial, int n) {
    __shared__ int s[1024];
    int tid = threadIdx.x;
    int i = blockIdx.x * 1024 + tid;
    int v = (i < n) ? cnt[i] : 0;
    s[tid] = v;
    __syncthreads();
    for (int off = 1; off < 1024; off <<= 1) {
        int t = (tid >= off) ? s[tid - off] : 0;
        __syncthreads();
        s[tid] += t;
        __syncthreads();
    }
    excl[i] = s[tid] - v;
    if (tid == 1023) partial[blockIdx.x] = s[1023];
}

__global__ __launch_bounds__(128) void k_scan2(int* __restrict__ partial, int nb) {
    __shared__ int s[128];
    int tid = threadIdx.x;
    int v = (tid < nb) ? partial[tid] : 0;
    s[tid] = v;
    __syncthreads();
    for (int off = 1; off < 128; off <<= 1) {
        int t = (tid >= off) ? s[tid - off] : 0;
        __syncthreads();
        s[tid] += t;
        __syncthreads();
    }
    if (tid < nb) partial[tid] = s[tid] - v;  // exclusive
}

__global__ __launch_bounds__(1024) void k_scan3(int* __restrict__ row_start,
                                                int* __restrict__ fill,
                                                const int* __restrict__ partial) {
    int i = blockIdx.x * 1024 + threadIdx.x;
    int v = row_start[i] + partial[blockIdx.x];
    row_start[i] = v;
    fill[i] = v;
}

// ---- bucket edges into CSR slots: packed (src, raw weight) ---------------

__global__ void k_bucket(const int* __restrict__ src, const int* __restrict__ dst,
                         const float* __restrict__ w, int* __restrict__ fill,
                         int2* __restrict__ edges, int E) {
    int e = blockIdx.x * blockDim.x + threadIdx.x;
    if (e < E) {
        int s = __builtin_nontemporal_load(src + e);
        int d = __builtin_nontemporal_load(dst + e);
        float wv = __builtin_nontemporal_load(w + e);
        int p = atomicAdd(&fill[d], 1);
        edges[p] = make_int2(s, __float_as_int(wv));
    }
}

// ---- weighted degree per row (coalesced over own row), then dinv ---------

__global__ __launch_bounds__(256) void k_deg(
    const int* __restrict__ row_start, const int* __restrict__ cnt,
    const int2* __restrict__ edges, float* __restrict__ deg, int n, int nwaves) {
    int lane = threadIdx.x & 63;
    int wv = (blockIdx.x * blockDim.x + threadIdx.x) >> 6;
    for (int row = wv; row < n; row += nwaves) {
        int beg = row_start[row], c = cnt[row];
        float s = 0.f;
        for (int j = lane; j < c; j += 64)
            s += __int_as_float(edges[beg + j].y);
#pragma unroll
        for (int off = 32; off > 0; off >>= 1) s += __shfl_xor(s, off, 64);
        if (lane == 0) deg[row] = 1.0f + s;
    }
}

__global__ void k_dinv(float* __restrict__ deg, int n) {
    int i = blockIdx.x * blockDim.x + threadIdx.x;
    if (i < n) {
        float d = deg[i];
        deg[i] = d > 0.f ? rsqrtf(fmaxf(d, 1e-12f)) : 0.f;
    }
}

// ---- finalize per-edge norm: ev.y = dinv[src]*w*dinv[row] ----------------

__global__ __launch_bounds__(256) void k_normp(
    const int* __restrict__ row_start, const int* __restrict__ cnt,
    int2* __restrict__ edges, const float* __restrict__ dinv, int n, int nwaves) {
    int lane = threadIdx.x & 63;
    int wv = (blockIdx.x * blockDim.x + threadIdx.x) >> 6;
    for (int row = wv; row < n; row += nwaves) {
        int beg = row_start[row], c = cnt[row];
        float dr = dinv[row];
        for (int j = lane; j < c; j += 64) {
            int2 ev = edges[beg + j];
            float nv = dinv[ev.x] * __int_as_float(ev.y) * dr;
            edges[beg + j].y = __float_as_int(nv);
        }
    }
}

// ---- emb f32 -> bf16 table -----------------------------------------------

__global__ void k_cvt(const float* __restrict__ x, unsigned short* __restrict__ xb,
                      int n4) {
    int i = blockIdx.x * blockDim.x + threadIdx.x;
    if (i < n4) {
        float4 v = ((const float4*)x)[i];
        ushort4 o;
        o.x = f2bf(v.x); o.y = f2bf(v.y); o.z = f2bf(v.z); o.w = f2bf(v.w);
        ((ushort4*)xb)[i] = o;
    }
}

// ---- fused layer: y = leaky((A @ x) @ W + b) ------------------------------
// Persistent blocks; one wave per dst row (grid-stride). Lane-parallel edge
// loads (one coalesced 64-edge load per row, shfl broadcast), 8-deep gather
// pipeline, in-wave shfl GEMM against W in LDS.

__global__ __launch_bounds__(256) void k_layer(
    const unsigned short* __restrict__ xb, const int* __restrict__ row_start,
    const int* __restrict__ cnt, const int2* __restrict__ edges,
    const float* __restrict__ dinv, const float* __restrict__ W,
    const float* __restrict__ b, unsigned short* __restrict__ yb, int n,
    int nwaves) {
    __shared__ float Ws[64 * 64];
    int tid = threadIdx.x;
    const float4* Wv = (const float4*)W;
    float4* Wsv = (float4*)Ws;
#pragma unroll
    for (int i = 0; i < 4; i++) Wsv[tid + i * 256] = Wv[tid + i * 256];
    __syncthreads();
    int lane = tid & 63;
    int wv = (blockIdx.x * 256 + tid) >> 6;
    float bl = b[lane];
    for (int row = wv; row < n; row += nwaves) {
        int beg = row_start[row];
        int c = cnt[row];
        float di = dinv[row];
        float acc = di * di * bf2f(xb[(size_t)row * 64 + lane]);
        const long long* ep = (const long long*)(edges + beg);
        for (int base = 0; base < c; base += 64) {
            int rem = c - base; if (rem > 64) rem = 64;
            long long ev = 0;
            if (lane < rem) ev = __builtin_nontemporal_load(ep + base + lane);
            int evs = (int)ev;
            int evn = (int)(ev >> 32);
            int k = 0;
            for (; k + 8 <= rem; k += 8) {
                int s[8]; float nv[8], xv[8];
#pragma unroll
                for (int q = 0; q < 8; q++) {
                    s[q] = __shfl(evs, k + q, 64);
                    nv[q] = __int_as_float(__shfl(evn, k + q, 64));
                }
#pragma unroll
                for (int q = 0; q < 8; q++)
                    xv[q] = bf2f(xb[(size_t)s[q] * 64 + lane]);
#pragma unroll
                for (int q = 0; q < 8; q++) acc = fmaf(nv[q], xv[q], acc);
            }
            for (; k < rem; k++) {
                int s0 = __shfl(evs, k, 64);
                float nv0 = __int_as_float(__shfl(evn, k, 64));
                acc = fmaf(nv0, bf2f(xb[(size_t)s0 * 64 + lane]), acc);
            }
        }
        float o = bl;
#pragma unroll
        for (int k = 0; k < 64; k++) {
            float xk = __shfl(acc, k, 64);
            o = fmaf(xk, Ws[k * 64 + lane], o);
        }
        yb[(size_t)row * 64 + lane] = f2bf(leaky(o));
    }
}

// ---- head MLP (bf16 activations in) --------------------------------------

__global__ __launch_bounds__(256) void k_head(
    const unsigned short* __restrict__ xb, const int* __restrict__ home,
    const int* __restrict__ away, const float* __restrict__ W1,
    const float* __restrict__ b1, const float* __restrict__ W3,
    const float* __restrict__ b3, float* __restrict__ z2, int B) {
    __shared__ float W1s[128 * 6];
    __shared__ float b1s[6], W3s[18], b3s[3];
    int tid = threadIdx.x;
    for (int i = tid; i < 768; i += 256) W1s[i] = W1[i];
    if (tid < 6) b1s[tid] = b1[tid];
    if (tid < 18) W3s[tid] = W3[tid];
    if (tid < 3) b3s[tid] = b3[tid];
    __syncthreads();
    int i = blockIdx.x * 256 + tid;
    if (i >= B) return;
    float z1[6];
#pragma unroll
    for (int j = 0; j < 6; j++) z1[j] = b1s[j];
    const uint4* rows[2];
    rows[0] = (const uint4*)(xb + (size_t)home[i] * 64);
    rows[1] = (const uint4*)(xb + (size_t)away[i] * 64);
#pragma unroll
    for (int h = 0; h < 2; h++) {
        const uint4* r = rows[h];
        int base = h * 64;
#pragma unroll
        for (int k = 0; k < 8; k++) {
            uint4 v = r[k];
            unsigned uu[4] = {v.x, v.y, v.z, v.w};
#pragma unroll
            for (int t = 0; t < 4; t++) {
                float2 f = bf2x2(uu[t]);
                int d = base + k * 8 + t * 2;
#pragma unroll
                for (int j = 0; j < 6; j++) {
                    z1[j] = fmaf(f.x, W1s[d * 6 + j], z1[j]);
                    z1[j] = fmaf(f.y, W1s[(d + 1) * 6 + j], z1[j]);
                }
            }
        }
    }
#pragma unroll
    for (int j = 0; j < 6; j++) z1[j] = leaky(z1[j]);
#pragma unroll
    for (int c = 0; c < 3; c++) {
        float s = b3s[c];
#pragma unroll
        for (int j = 0; j < 6; j++) s = fmaf(z1[j], W3s[j * 3 + c], s);
        z2[(size_t)i * 3 + c] = leaky(s);
    }
}

// ---- column-wise log-softmax ---------------------------------------------

__global__ __launch_bounds__(1024) void k_stats(const float* __restrict__ z2,
                                                float* __restrict__ stats, int B) {
    __shared__ float red[3][1024];
    int tid = threadIdx.x;
    float m[3] = {-1e30f, -1e30f, -1e30f};
    for (int i = tid; i < B; i += 1024) {
        m[0] = fmaxf(m[0], z2[3 * i + 0]);
        m[1] = fmaxf(m[1], z2[3 * i + 1]);
        m[2] = fmaxf(m[2], z2[3 * i + 2]);
    }
    for (int c = 0; c < 3; c++) red[c][tid] = m[c];
    __syncthreads();
    for (int s = 512; s > 0; s >>= 1) {
        if (tid < s)
            for (int c = 0; c < 3; c++) red[c][tid] = fmaxf(red[c][tid], red[c][tid + s]);
        __syncthreads();
    }
    float M[3];
    for (int c = 0; c < 3; c++) M[c] = red[c][0];
    __syncthreads();
    float sum[3] = {0.f, 0.f, 0.f};
    for (int i = tid; i < B; i += 1024) {
        sum[0] += expf(z2[3 * i + 0] - M[0]);
        sum[1] += expf(z2[3 * i + 1] - M[1]);
        sum[2] += expf(z2[3 * i + 2] - M[2]);
    }
    for (int c = 0; c < 3; c++) red[c][tid] = sum[c];
    __syncthreads();
    for (int s = 512; s > 0; s >>= 1) {
        if (tid < s)
            for (int c = 0; c < 3; c++) red[c][tid] += red[c][tid + s];
        __syncthreads();
    }
    if (tid == 0)
        for (int c = 0; c < 3; c++) { stats[c] = M[c]; stats[3 + c] = logf(red[c][0]); }
}

__global__ void k_final(const float* __restrict__ z2, const float* __restrict__ stats,
                        float* __restrict__ out, int n) {
    int i = blockIdx.x * blockDim.x + threadIdx.x;
    if (i < n) {
        int c = i % 3;
        out[i] = z2[i] - stats[c] - stats[3 + c];
    }
}

// ---- launch --------------------------------------------------------------

extern "C" void kernel_launch(void* const* d_in, const int* in_sizes, int n_in,
                              void* d_out, int out_size, void* d_ws, size_t ws_size,
                              hipStream_t stream) {
    const int*   edge_index = (const int*)d_in[0];
    const int*   src  = edge_index;
    const int*   dst  = edge_index + N_EDGES;
    const float* ew   = (const float*)d_in[1];
    const int*   home = (const int*)d_in[2];
    const int*   away = (const int*)d_in[3];
    const float* emb  = (const float*)d_in[4];
    const float* W0 = (const float*)d_in[5];  const float* b0 = (const float*)d_in[6];
    const float* W1 = (const float*)d_in[7];  const float* b1 = (const float*)d_in[8];
    const float* W2 = (const float*)d_in[9];  const float* b2 = (const float*)d_in[10];
    const float* l1W = (const float*)d_in[11]; const float* l1b = (const float*)d_in[12];
    const float* l3W = (const float*)d_in[13]; const float* l3b = (const float*)d_in[14];

    char* p = (char*)d_ws;
    float*          dinv      = (float*)p;          p += NPAD * 4;
    int*            cnt       = (int*)p;            p += NPAD * 4;
    int*            fill      = (int*)p;            p += NPAD * 4;
    int*            row_start = (int*)p;            p += NPAD * 4;
    int*            partial   = (int*)p;            p += 128 * 4;
    int2*           edges     = (int2*)p;           p += (size_t)N_EDGES * 8;
    unsigned short* xbA       = (unsigned short*)p; p += (size_t)N_TEAMS * 64 * 2;
    unsigned short* xbB       = (unsigned short*)p; p += (size_t)N_TEAMS * 64 * 2;
    float*          z2        = (float*)p;          p += (size_t)BATCH * 3 * 4;
    float*          stats     = (float*)p;

    const int scanBlocks = NPAD / 1024;  // 98

    // ---- CSR build (once, reused by all 3 layers) ----
    k_zero<<<NPAD / 256, 256, 0, stream>>>(cnt, NPAD);
    k_cnt<<<(N_EDGES + 255) / 256, 256, 0, stream>>>(dst, cnt, N_EDGES);
    k_scan1<<<scanBlocks, 1024, 0, stream>>>(cnt, row_start, partial, N_TEAMS);
    k_scan2<<<1, 128, 0, stream>>>(partial, scanBlocks);
    k_scan3<<<scanBlocks, 1024, 0, stream>>>(row_start, fill, partial);
    k_bucket<<<(N_EDGES + 255) / 256, 256, 0, stream>>>(src, dst, ew, fill, edges, N_EDGES);

    const int PWAVES = 1024 * 4;  // persistent helper waves (1024 blocks x 4)
    k_deg<<<1024, 256, 0, stream>>>(row_start, cnt, edges, dinv, N_TEAMS, PWAVES);
    k_dinv<<<(N_TEAMS + 255) / 256, 256, 0, stream>>>(dinv, N_TEAMS);
    k_normp<<<1024, 256, 0, stream>>>(row_start, cnt, edges, dinv, N_TEAMS, PWAVES);
    k_cvt<<<(N_TEAMS * 64 / 4 + 255) / 256, 256, 0, stream>>>(emb, xbA, N_TEAMS * 64 / 4);

    const int LBLOCKS = 2048;
    const int LWAVES  = LBLOCKS * 4;

    // layer 0..2 fused: agg + GEMM + bias + leaky
    k_layer<<<LBLOCKS, 256, 0, stream>>>(xbA, row_start, cnt, edges, dinv, W0, b0, xbB, N_TEAMS, LWAVES);
    k_layer<<<LBLOCKS, 256, 0, stream>>>(xbB, row_start, cnt, edges, dinv, W1, b1, xbA, N_TEAMS, LWAVES);
    k_layer<<<LBLOCKS, 256, 0, stream>>>(xbA, row_start, cnt, edges, dinv, W2, b2, xbB, N_TEAMS, LWAVES);

    // head + column log-softmax
    k_head<<<(BATCH + 255) / 256, 256, 0, stream>>>(xbB, home, away, l1W, l1b, l3W, l3b, z2, BATCH);
    k_stats<<<1, 1024, 0, stream>>>(z2, stats, BATCH);
    k_final<<<(BATCH * 3 + 255) / 256, 256, 0, stream>>>(z2, stats, (float*)d_out, BATCH * 3);
}

// Round 6
// 1026.920 us; speedup vs baseline: 1.0279x; 1.0279x over previous
//
#include <hip/hip_runtime.h>
#include <math.h>

#define N_TEAMS 100000
#define N_EDGES 1600000
#define BATCH   16384
#define DIM     64
#define SLOPE   0.01f
#define NPAD    100352                 // 98 * 1024
#define SS      ((size_t)NPAD * 8)    // slice stride in elements (bf16)

__device__ __forceinline__ float leaky(float v) { return v > 0.f ? v : SLOPE * v; }

__device__ __forceinline__ float bf2f(unsigned short u) {
    return __uint_as_float(((unsigned)u) << 16);
}
__device__ __forceinline__ unsigned short f2bf(float f) {
    unsigned b = __float_as_uint(f);
    unsigned r = b + 0x7FFFu + ((b >> 16) & 1u);  // RNE
    return (unsigned short)(r >> 16);
}

// ---- setup ---------------------------------------------------------------

__global__ void k_zero(int* __restrict__ cnt, int n) {
    int i = blockIdx.x * blockDim.x + threadIdx.x;
    if (i < n) cnt[i] = 0;
}

__global__ void k_cnt(const int* __restrict__ dst, int* __restrict__ cnt, int E) {
    int e = blockIdx.x * blockDim.x + threadIdx.x;
    if (e < E) atomicAdd(&cnt[__builtin_nontemporal_load(dst + e)], 1);
}

// ---- 2-level exclusive scan of cnt -> row_start (+ fill copy) ------------

__global__ __launch_bounds__(1024) void k_scan1(const int* __restrict__ cnt,
                                                int* __restrict__ excl,
                                                int* __restrict__ partial, int n) {
    __shared__ int s[1024];
    int tid = threadIdx.x;
    int i = blockIdx.x * 1024 + tid;
    int v = (i < n) ? cnt[i] : 0;
    s[tid] = v;
    __syncthreads();
    for (int off = 1; off < 1024; off <<= 1) {
        int t = (tid >= off) ? s[tid - off] : 0;
        __syncthreads();
        s[tid] += t;
        __syncthreads();
    }
    excl[i] = s[tid] - v;
    if (tid == 1023) partial[blockIdx.x] = s[1023];
}

__global__ __launch_bounds__(128) void k_scan2(int* __restrict__ partial, int nb) {
    __shared__ int s[128];
    int tid = threadIdx.x;
    int v = (tid < nb) ? partial[tid] : 0;
    s[tid] = v;
    __syncthreads();
    for (int off = 1; off < 128; off <<= 1) {
        int t = (tid >= off) ? s[tid - off] : 0;
        __syncthreads();
        s[tid] += t;
        __syncthreads();
    }
    if (tid < nb) partial[tid] = s[tid] - v;  // exclusive
}

__global__ __launch_bounds__(1024) void k_scan3(int* __restrict__ row_start,
                                                int* __restrict__ fill,
                                                const int* __restrict__ partial) {
    int i = blockIdx.x * 1024 + threadIdx.x;
    int v = row_start[i] + partial[blockIdx.x];
    row_start[i] = v;
    fill[i] = v;
}

// ---- bucket edges into CSR slots: packed (src, raw weight) ---------------

__global__ void k_bucket(const int* __restrict__ src, const int* __restrict__ dst,
                         const float* __restrict__ w, int* __restrict__ fill,
                         int2* __restrict__ edges, int E) {
    int e = blockIdx.x * blockDim.x + threadIdx.x;
    if (e < E) {
        int s = __builtin_nontemporal_load(src + e);
        int d = __builtin_nontemporal_load(dst + e);
        float wv = __builtin_nontemporal_load(w + e);
        int p = atomicAdd(&fill[d], 1);
        edges[p] = make_int2(s, __float_as_int(wv));
    }
}

// ---- dinv: thread per row, sum raw weights over own CSR range ------------

__global__ void k_dinv(const int* __restrict__ row_start,
                       const int* __restrict__ edges_i,  // int view of edges
                       float* __restrict__ dinv, int n) {
    int r = blockIdx.x * blockDim.x + threadIdx.x;
    if (r >= n) return;
    int beg = row_start[r], end = row_start[r + 1];
    float s = 1.0f;  // self-loop
    for (int j = beg; j < end; j++) s += __int_as_float(edges_i[2 * j + 1]);
    dinv[r] = rsqrtf(fmaxf(s, 1e-12f));
}

// ---- emb -> scaled slice-major bf16: xs[s][row][8] = dinv[row]*emb[row][s*8+d]

__global__ void k_cvt(const float* __restrict__ emb, const float* __restrict__ dinv,
                      unsigned short* __restrict__ xs, int n8) {
    int t = blockIdx.x * blockDim.x + threadIdx.x;
    if (t >= n8) return;
    int row = t >> 3, s = t & 7;
    float di = dinv[row];
    const float* e = emb + (size_t)row * 64 + s * 8;
    ushort4 lo, hi;
    lo.x = f2bf(di * e[0]); lo.y = f2bf(di * e[1]);
    lo.z = f2bf(di * e[2]); lo.w = f2bf(di * e[3]);
    hi.x = f2bf(di * e[4]); hi.y = f2bf(di * e[5]);
    hi.z = f2bf(di * e[6]); hi.w = f2bf(di * e[7]);
    ushort4* o = (ushort4*)(xs + (size_t)s * SS + (size_t)row * 8);
    o[0] = lo; o[1] = hi;
}

// ---- sliced aggregation: agg[s][row][d] = dinv_row*(sum_e w_e*x'[src][s,d] + x'[row][s,d])
// blockIdx%8 = slice (XCD-local 1.6MB gather table). Wave: 8 edges x 8 dims.

__global__ __launch_bounds__(256) void k_aggs(
    const unsigned short* __restrict__ xs, const int* __restrict__ row_start,
    const long long* __restrict__ edges, const float* __restrict__ dinv,
    unsigned short* __restrict__ out, int n) {
    int tid = threadIdx.x;
    int lane = tid & 63;
    int slice = blockIdx.x & 7;
    int q = (blockIdx.x >> 3) * 4 + (tid >> 6);  // wave id within slice [0,1024)
    const int RP = (N_TEAMS + 1023) / 1024;      // 98 rows per wave
    int r0 = q * RP;
    int r1 = min(r0 + RP, n);
    int eg = lane >> 3;   // edge slot in chunk
    int d  = lane & 7;    // dim within slice
    const unsigned short* xsl = xs + (size_t)slice * SS;
    unsigned short* osl = out + (size_t)slice * SS;
    for (int row = r0; row < r1; ++row) {
        int beg = row_start[row];
        int c = row_start[row + 1] - beg;
        const long long* ep = edges + beg;
        float acc = 0.f;
        int e = eg;
        long long ev = (e < c) ? ep[e] : 0;   // w bits = 0 -> contributes 0
        for (int base = 0; base < c; base += 8) {
            int sidx = (int)ev;
            float w = __int_as_float((int)(ev >> 32));
            float x = bf2f(xsl[(size_t)sidx * 8 + d]);   // gather (L2-local slice)
            int e2 = base + 8 + eg;
            long long evn = (e2 < c) ? ep[e2] : 0;       // prefetch next chunk
            acc = fmaf(w, x, acc);
            ev = evn;
        }
        acc += __shfl_xor(acc, 8, 64);
        acc += __shfl_xor(acc, 16, 64);
        acc += __shfl_xor(acc, 32, 64);
        float self = bf2f(xsl[(size_t)row * 8 + d]);
        float res = dinv[row] * (acc + self);
        if (lane < 8) osl[(size_t)row * 8 + d] = f2bf(res);
    }
}

// ---- gemm: y = leaky(agg @ W + b) [optionally * dinv], slice-major IO ----

__global__ __launch_bounds__(256) void k_gemm2(
    const unsigned short* __restrict__ in, const float* __restrict__ W,
    const float* __restrict__ b, const float* __restrict__ dinv, int scale_out,
    unsigned short* __restrict__ out, int n) {
    __shared__ float Ws[64 * 64];
    __shared__ float xsh[16][68];
    int tid = threadIdx.x;
    const float4* Wv = (const float4*)W;
    float4* Wsv = (float4*)Ws;
#pragma unroll
    for (int i = 0; i < 4; i++) Wsv[tid + i * 256] = Wv[tid + i * 256];
    int r0 = blockIdx.x * 16;
    {
        int s = tid >> 5, row = (tid & 31) >> 1, half = tid & 1;
        uint2 v = *(const uint2*)(in + (size_t)s * SS + (size_t)(r0 + row) * 8 + half * 4);
        int col = s * 8 + half * 4;
        xsh[row][col + 0] = bf2f((unsigned short)(v.x & 0xFFFF));
        xsh[row][col + 1] = bf2f((unsigned short)(v.x >> 16));
        xsh[row][col + 2] = bf2f((unsigned short)(v.y & 0xFFFF));
        xsh[row][col + 3] = bf2f((unsigned short)(v.y >> 16));
    }
    __syncthreads();
    int c = tid & 63, rr = tid >> 6;
    float acc[4] = {0.f, 0.f, 0.f, 0.f};
#pragma unroll
    for (int k = 0; k < 64; k++) {
        float wv = Ws[k * 64 + c];
#pragma unroll
        for (int i = 0; i < 4; i++) acc[i] = fmaf(xsh[4 * i + rr][k], wv, acc[i]);
    }
    float bc = b[c];
    int so = c >> 3, dd = c & 7;
#pragma unroll
    for (int i = 0; i < 4; i++) {
        int row = r0 + 4 * i + rr;
        if (row < n) {
            float v = leaky(acc[i] + bc);
            if (scale_out) v *= dinv[row];
            out[(size_t)so * SS + (size_t)row * 8 + dd] = f2bf(v);
        }
    }
}

// ---- head MLP (slice-major bf16 activations in) --------------------------

__global__ __launch_bounds__(256) void k_head(
    const unsigned short* __restrict__ xb, const int* __restrict__ home,
    const int* __restrict__ away, const float* __restrict__ W1,
    const float* __restrict__ b1, const float* __restrict__ W3,
    const float* __restrict__ b3, float* __restrict__ z2, int B) {
    __shared__ float W1s[128 * 6];
    __shared__ float b1s[6], W3s[18], b3s[3];
    int tid = threadIdx.x;
    for (int i = tid; i < 768; i += 256) W1s[i] = W1[i];
    if (tid < 6) b1s[tid] = b1[tid];
    if (tid < 18) W3s[tid] = W3[tid];
    if (tid < 3) b3s[tid] = b3[tid];
    __syncthreads();
    int i = blockIdx.x * 256 + tid;
    if (i >= B) return;
    float z1[6];
#pragma unroll
    for (int j = 0; j < 6; j++) z1[j] = b1s[j];
    int teams[2] = {home[i], away[i]};
#pragma unroll
    for (int h = 0; h < 2; h++) {
        size_t rowoff = (size_t)teams[h] * 8;
#pragma unroll
        for (int s = 0; s < 8; s++) {
            uint4 v = *(const uint4*)(xb + (size_t)s * SS + rowoff);
            unsigned uu[4] = {v.x, v.y, v.z, v.w};
            int base = h * 64 + s * 8;
#pragma unroll
            for (int t = 0; t < 4; t++) {
                float fx = bf2f((unsigned short)(uu[t] & 0xFFFF));
                float fy = bf2f((unsigned short)(uu[t] >> 16));
                int dd = base + t * 2;
#pragma unroll
                for (int j = 0; j < 6; j++) {
                    z1[j] = fmaf(fx, W1s[dd * 6 + j], z1[j]);
                    z1[j] = fmaf(fy, W1s[(dd + 1) * 6 + j], z1[j]);
                }
            }
        }
    }
#pragma unroll
    for (int j = 0; j < 6; j++) z1[j] = leaky(z1[j]);
#pragma unroll
    for (int c = 0; c < 3; c++) {
        float s = b3s[c];
#pragma unroll
        for (int j = 0; j < 6; j++) s = fmaf(z1[j], W3s[j * 3 + c], s);
        z2[(size_t)i * 3 + c] = leaky(s);
    }
}

// ---- column-wise log-softmax ---------------------------------------------

__global__ __launch_bounds__(1024) void k_stats(const float* __restrict__ z2,
                                                float* __restrict__ stats, int B) {
    __shared__ float red[3][1024];
    int tid = threadIdx.x;
    float m[3] = {-1e30f, -1e30f, -1e30f};
    for (int i = tid; i < B; i += 1024) {
        m[0] = fmaxf(m[0], z2[3 * i + 0]);
        m[1] = fmaxf(m[1], z2[3 * i + 1]);
        m[2] = fmaxf(m[2], z2[3 * i + 2]);
    }
    for (int c = 0; c < 3; c++) red[c][tid] = m[c];
    __syncthreads();
    for (int s = 512; s > 0; s >>= 1) {
        if (tid < s)
            for (int c = 0; c < 3; c++) red[c][tid] = fmaxf(red[c][tid], red[c][tid + s]);
        __syncthreads();
    }
    float M[3];
    for (int c = 0; c < 3; c++) M[c] = red[c][0];
    __syncthreads();
    float sum[3] = {0.f, 0.f, 0.f};
    for (int i = tid; i < B; i += 1024) {
        sum[0] += expf(z2[3 * i + 0] - M[0]);
        sum[1] += expf(z2[3 * i + 1] - M[1]);
        sum[2] += expf(z2[3 * i + 2] - M[2]);
    }
    for (int c = 0; c < 3; c++) red[c][tid] = sum[c];
    __syncthreads();
    for (int s = 512; s > 0; s >>= 1) {
        if (tid < s)
            for (int c = 0; c < 3; c++) red[c][tid] += red[c][tid + s];
        __syncthreads();
    }
    if (tid == 0)
        for (int c = 0; c < 3; c++) { stats[c] = M[c]; stats[3 + c] = logf(red[c][0]); }
}

__global__ void k_final(const float* __restrict__ z2, const float* __restrict__ stats,
                        float* __restrict__ out, int n) {
    int i = blockIdx.x * blockDim.x + threadIdx.x;
    if (i < n) {
        int c = i % 3;
        out[i] = z2[i] - stats[c] - stats[3 + c];
    }
}

// ---- launch --------------------------------------------------------------

extern "C" void kernel_launch(void* const* d_in, const int* in_sizes, int n_in,
                              void* d_out, int out_size, void* d_ws, size_t ws_size,
                              hipStream_t stream) {
    const int*   edge_index = (const int*)d_in[0];
    const int*   src  = edge_index;
    const int*   dst  = edge_index + N_EDGES;
    const float* ew   = (const float*)d_in[1];
    const int*   home = (const int*)d_in[2];
    const int*   away = (const int*)d_in[3];
    const float* emb  = (const float*)d_in[4];
    const float* W0 = (const float*)d_in[5];  const float* b0 = (const float*)d_in[6];
    const float* W1 = (const float*)d_in[7];  const float* b1 = (const float*)d_in[8];
    const float* W2 = (const float*)d_in[9];  const float* b2 = (const float*)d_in[10];
    const float* l1W = (const float*)d_in[11]; const float* l1b = (const float*)d_in[12];
    const float* l3W = (const float*)d_in[13]; const float* l3b = (const float*)d_in[14];

    char* p = (char*)d_ws;
    float*          dinv      = (float*)p;          p += NPAD * 4;
    int*            cnt       = (int*)p;            p += NPAD * 4;
    int*            fill      = (int*)p;            p += NPAD * 4;
    int*            row_start = (int*)p;            p += (NPAD + 1024) * 4;
    int*            partial   = (int*)p;            p += 128 * 4;
    int2*           edges     = (int2*)p;           p += (size_t)N_EDGES * 8;
    unsigned short* xsA       = (unsigned short*)p; p += SS * 8 * 2;
    unsigned short* xsB       = (unsigned short*)p; p += SS * 8 * 2;
    unsigned short* aggS      = (unsigned short*)p; p += SS * 8 * 2;
    float*          z2        = (float*)p;          p += (size_t)BATCH * 3 * 4;
    float*          stats     = (float*)p;

    const int scanBlocks = NPAD / 1024;  // 98

    // ---- CSR build (once, reused by all 3 layers) ----
    k_zero<<<NPAD / 256, 256, 0, stream>>>(cnt, NPAD);
    k_cnt<<<(N_EDGES + 255) / 256, 256, 0, stream>>>(dst, cnt, N_EDGES);
    k_scan1<<<scanBlocks, 1024, 0, stream>>>(cnt, row_start, partial, N_TEAMS);
    k_scan2<<<1, 128, 0, stream>>>(partial, scanBlocks);
    k_scan3<<<scanBlocks, 1024, 0, stream>>>(row_start, fill, partial);
    k_bucket<<<(N_EDGES + 255) / 256, 256, 0, stream>>>(src, dst, ew, fill, edges, N_EDGES);
    k_dinv<<<(N_TEAMS + 255) / 256, 256, 0, stream>>>(row_start, (const int*)edges, dinv, N_TEAMS);
    k_cvt<<<(N_TEAMS * 8) / 256, 256, 0, stream>>>(emb, dinv, xsA, N_TEAMS * 8);

    const int AGG_BLOCKS = 2048;                 // 8 slices x 256 block-groups
    const int GEMM_BLOCKS = (N_TEAMS + 15) / 16; // 6250

    // layer 0: xsA -> aggS -> xsB (scaled)
    k_aggs<<<AGG_BLOCKS, 256, 0, stream>>>(xsA, row_start, (const long long*)edges, dinv, aggS, N_TEAMS);
    k_gemm2<<<GEMM_BLOCKS, 256, 0, stream>>>(aggS, W0, b0, dinv, 1, xsB, N_TEAMS);
    // layer 1: xsB -> aggS -> xsA (scaled)
    k_aggs<<<AGG_BLOCKS, 256, 0, stream>>>(xsB, row_start, (const long long*)edges, dinv, aggS, N_TEAMS);
    k_gemm2<<<GEMM_BLOCKS, 256, 0, stream>>>(aggS, W1, b1, dinv, 1, xsA, N_TEAMS);
    // layer 2: xsA -> aggS -> xsB (unscaled, for head)
    k_aggs<<<AGG_BLOCKS, 256, 0, stream>>>(xsA, row_start, (const long long*)edges, dinv, aggS, N_TEAMS);
    k_gemm2<<<GEMM_BLOCKS, 256, 0, stream>>>(aggS, W2, b2, dinv, 0, xsB, N_TEAMS);

    // head + column log-softmax
    k_head<<<(BATCH + 255) / 256, 256, 0, stream>>>(xsB, home, away, l1W, l1b, l3W, l3b, z2, BATCH);
    k_stats<<<1, 1024, 0, stream>>>(z2, stats, BATCH);
    k_final<<<(BATCH * 3 + 255) / 256, 256, 0, stream>>>(z2, stats, (float*)d_out, BATCH * 3);
}

// Round 7
// 960.353 us; speedup vs baseline: 1.0991x; 1.0693x over previous
//
#include <hip/hip_runtime.h>
#include <math.h>

#define N_TEAMS 100000
#define N_EDGES 1600000
#define BATCH   16384
#define DIM     64
#define SLOPE   0.01f
#define NPAD    100352  // 98 * 1024

__device__ __forceinline__ float leaky(float v) { return v > 0.f ? v : SLOPE * v; }

__device__ __forceinline__ float bf2f(unsigned short u) {
    return __uint_as_float(((unsigned)u) << 16);
}
__device__ __forceinline__ unsigned short f2bf(float f) {
    unsigned b = __float_as_uint(f);
    unsigned r = b + 0x7FFFu + ((b >> 16) & 1u);  // RNE
    return (unsigned short)(r >> 16);
}

// ---- setup ---------------------------------------------------------------

__global__ void k_zero(int* __restrict__ cnt, int n) {
    int i = blockIdx.x * blockDim.x + threadIdx.x;
    if (i < n) cnt[i] = 0;
}

__global__ void k_cnt(const int* __restrict__ dst, int* __restrict__ cnt, int E) {
    int e = blockIdx.x * blockDim.x + threadIdx.x;
    if (e < E) atomicAdd(&cnt[__builtin_nontemporal_load(dst + e)], 1);
}

// ---- 2-level exclusive scan of cnt -> row_start (+ fill copy) ------------

__global__ __launch_bounds__(1024) void k_scan1(const int* __restrict__ cnt,
                                                int* __restrict__ excl,
                                                int* __restrict__ partial, int n) {
    __shared__ int s[1024];
    int tid = threadIdx.x;
    int i = blockIdx.x * 1024 + tid;
    int v = (i < n) ? cnt[i] : 0;
    s[tid] = v;
    __syncthreads();
    for (int off = 1; off < 1024; off <<= 1) {
        int t = (tid >= off) ? s[tid - off] : 0;
        __syncthreads();
        s[tid] += t;
        __syncthreads();
    }
    excl[i] = s[tid] - v;
    if (tid == 1023) partial[blockIdx.x] = s[1023];
}

__global__ __launch_bounds__(128) void k_scan2(int* __restrict__ partial, int nb) {
    __shared__ int s[128];
    int tid = threadIdx.x;
    int v = (tid < nb) ? partial[tid] : 0;
    s[tid] = v;
    __syncthreads();
    for (int off = 1; off < 128; off <<= 1) {
        int t = (tid >= off) ? s[tid - off] : 0;
        __syncthreads();
        s[tid] += t;
        __syncthreads();
    }
    if (tid < nb) partial[tid] = s[tid] - v;  // exclusive
}

__global__ __launch_bounds__(1024) void k_scan3(int* __restrict__ row_start,
                                                int* __restrict__ fill,
                                                const int* __restrict__ partial) {
    int i = blockIdx.x * 1024 + threadIdx.x;
    int v = row_start[i] + partial[blockIdx.x];
    row_start[i] = v;
    fill[i] = v;
}

// ---- bucket edges into CSR slots: packed (src, raw weight) ---------------

__global__ void k_bucket(const int* __restrict__ src, const int* __restrict__ dst,
                         const float* __restrict__ w, int* __restrict__ fill,
                         int2* __restrict__ edges, int E) {
    int e = blockIdx.x * blockDim.x + threadIdx.x;
    if (e < E) {
        int s = __builtin_nontemporal_load(src + e);
        int d = __builtin_nontemporal_load(dst + e);
        float wv = __builtin_nontemporal_load(w + e);
        int p = atomicAdd(&fill[d], 1);
        edges[p] = make_int2(s, __float_as_int(wv));
    }
}

// ---- dinv: thread per row, sum raw weights over own CSR range ------------

__global__ void k_dinv(const int* __restrict__ row_start,
                       const int* __restrict__ edges_i,  // int view of edges
                       float* __restrict__ dinv, int n) {
    int r = blockIdx.x * blockDim.x + threadIdx.x;
    if (r >= n) return;
    int beg = row_start[r], end = row_start[r + 1];
    float s = 1.0f;  // self-loop
    for (int j = beg; j < end; j++) s += __int_as_float(edges_i[2 * j + 1]);
    dinv[r] = rsqrtf(fmaxf(s, 1e-12f));
}

// ---- emb -> pre-scaled bf16 table: xb[row][d] = dinv[row]*emb[row][d] ----

__global__ void k_cvt(const float* __restrict__ emb, const float* __restrict__ dinv,
                      unsigned short* __restrict__ xb, int n4) {
    int i = blockIdx.x * blockDim.x + threadIdx.x;
    if (i >= n4) return;
    int row = i >> 4;  // 16 float4 per row
    float di = dinv[row];
    float4 v = ((const float4*)emb)[i];
    ushort4 o;
    o.x = f2bf(di * v.x); o.y = f2bf(di * v.y);
    o.z = f2bf(di * v.z); o.w = f2bf(di * v.w);
    ((ushort4*)xb)[i] = o;
}

// ---- fused layer: y = leaky((A @ x) @ W + b), persistent, 2 rows/wave ----
// Input table pre-scaled by dinv: agg_true[r] = dinv_r*(sum w_e*x'[src] + x'[r]).
// Two rows in lockstep -> 16 in-flight 128-B gathers per wave.
// scale_out: store dinv[row]*leaky(o) (pre-scale for next layer) or plain.

__global__ __launch_bounds__(256) void k_layer(
    const unsigned short* __restrict__ xb, const int* __restrict__ row_start,
    const long long* __restrict__ edges, const float* __restrict__ dinv,
    const float* __restrict__ W, const float* __restrict__ b,
    unsigned short* __restrict__ yb, int npairs, int nwaves, int scale_out) {
    __shared__ float Ws[64 * 64];
    int tid = threadIdx.x;
    const float4* Wv = (const float4*)W;
    float4* Wsv = (float4*)Ws;
#pragma unroll
    for (int i = 0; i < 4; i++) Wsv[tid + i * 256] = Wv[tid + i * 256];
    __syncthreads();
    int lane = tid & 63;
    int wv = blockIdx.x * 4 + (tid >> 6);
    float bl = b[lane];
    for (int pair = wv; pair < npairs; pair += nwaves) {
        int rowA = pair * 2, rowB = rowA + 1;
        int2 rs = *(const int2*)(row_start + rowA);   // [rowA], [rowA+1]
        int endB = row_start[rowB + 1];
        int begA = rs.x, cA = rs.y - rs.x;
        int begB = rs.y, cB = endB - rs.y;
        float2 dv = *(const float2*)(dinv + rowA);
        float accA = bf2f(xb[(size_t)rowA * 64 + lane]);
        float accB = bf2f(xb[(size_t)rowB * 64 + lane]);
        const long long* epA = edges + begA;
        const long long* epB = edges + begB;
        int cm = max(cA, cB);
        for (int base = 0; base < cm; base += 8) {
            int sA[8], sB[8];
            float nvA[8], nvB[8];
#pragma unroll
            for (int k = 0; k < 8; k++) {
                int i = base + k;
                long long e = __builtin_nontemporal_load(epA + min(i, cA - 1));
                if (i >= cA) e = 0;                       // src=0 (safe), w=0
                sA[k] = (int)e;
                nvA[k] = __int_as_float((int)(e >> 32));
                long long f = __builtin_nontemporal_load(epB + min(i, cB - 1));
                if (i >= cB) f = 0;
                sB[k] = (int)f;
                nvB[k] = __int_as_float((int)(f >> 32));
            }
            float xvA[8], xvB[8];
#pragma unroll
            for (int k = 0; k < 8; k++)
                xvA[k] = bf2f(xb[(size_t)sA[k] * 64 + lane]);
#pragma unroll
            for (int k = 0; k < 8; k++)
                xvB[k] = bf2f(xb[(size_t)sB[k] * 64 + lane]);
#pragma unroll
            for (int k = 0; k < 8; k++) accA = fmaf(nvA[k], xvA[k], accA);
#pragma unroll
            for (int k = 0; k < 8; k++) accB = fmaf(nvB[k], xvB[k], accB);
        }
        accA *= dv.x;
        accB *= dv.y;
        float oA = bl, oB = bl;
#pragma unroll
        for (int k = 0; k < 64; k++) {
            float w = Ws[k * 64 + lane];
            oA = fmaf(__shfl(accA, k, 64), w, oA);
            oB = fmaf(__shfl(accB, k, 64), w, oB);
        }
        oA = leaky(oA); oB = leaky(oB);
        if (scale_out) { oA *= dv.x; oB *= dv.y; }
        yb[(size_t)rowA * 64 + lane] = f2bf(oA);
        yb[(size_t)rowB * 64 + lane] = f2bf(oB);
    }
}

// ---- head MLP (bf16 activations in, row-major) ---------------------------

__global__ __launch_bounds__(256) void k_head(
    const unsigned short* __restrict__ xb, const int* __restrict__ home,
    const int* __restrict__ away, const float* __restrict__ W1,
    const float* __restrict__ b1, const float* __restrict__ W3,
    const float* __restrict__ b3, float* __restrict__ z2, int B) {
    __shared__ float W1s[128 * 6];
    __shared__ float b1s[6], W3s[18], b3s[3];
    int tid = threadIdx.x;
    for (int i = tid; i < 768; i += 256) W1s[i] = W1[i];
    if (tid < 6) b1s[tid] = b1[tid];
    if (tid < 18) W3s[tid] = W3[tid];
    if (tid < 3) b3s[tid] = b3[tid];
    __syncthreads();
    int i = blockIdx.x * 256 + tid;
    if (i >= B) return;
    float z1[6];
#pragma unroll
    for (int j = 0; j < 6; j++) z1[j] = b1s[j];
    const uint4* rows[2];
    rows[0] = (const uint4*)(xb + (size_t)home[i] * 64);
    rows[1] = (const uint4*)(xb + (size_t)away[i] * 64);
#pragma unroll
    for (int h = 0; h < 2; h++) {
        const uint4* r = rows[h];
        int base = h * 64;
#pragma unroll
        for (int k = 0; k < 8; k++) {   // 8 x uint4 = 64 bf16 dims
            uint4 v = r[k];
            unsigned uu[4] = {v.x, v.y, v.z, v.w};
#pragma unroll
            for (int t = 0; t < 4; t++) {
                float fx = bf2f((unsigned short)(uu[t] & 0xFFFF));
                float fy = bf2f((unsigned short)(uu[t] >> 16));
                int d = base + k * 8 + t * 2;
#pragma unroll
                for (int j = 0; j < 6; j++) {
                    z1[j] = fmaf(fx, W1s[d * 6 + j], z1[j]);
                    z1[j] = fmaf(fy, W1s[(d + 1) * 6 + j], z1[j]);
                }
            }
        }
    }
#pragma unroll
    for (int j = 0; j < 6; j++) z1[j] = leaky(z1[j]);
#pragma unroll
    for (int c = 0; c < 3; c++) {
        float s = b3s[c];
#pragma unroll
        for (int j = 0; j < 6; j++) s = fmaf(z1[j], W3s[j * 3 + c], s);
        z2[(size_t)i * 3 + c] = leaky(s);
    }
}

// ---- column-wise log-softmax ---------------------------------------------

__global__ __launch_bounds__(1024) void k_stats(const float* __restrict__ z2,
                                                float* __restrict__ stats, int B) {
    __shared__ float red[3][1024];
    int tid = threadIdx.x;
    float m[3] = {-1e30f, -1e30f, -1e30f};
    for (int i = tid; i < B; i += 1024) {
        m[0] = fmaxf(m[0], z2[3 * i + 0]);
        m[1] = fmaxf(m[1], z2[3 * i + 1]);
        m[2] = fmaxf(m[2], z2[3 * i + 2]);
    }
    for (int c = 0; c < 3; c++) red[c][tid] = m[c];
    __syncthreads();
    for (int s = 512; s > 0; s >>= 1) {
        if (tid < s)
            for (int c = 0; c < 3; c++) red[c][tid] = fmaxf(red[c][tid], red[c][tid + s]);
        __syncthreads();
    }
    float M[3];
    for (int c = 0; c < 3; c++) M[c] = red[c][0];
    __syncthreads();
    float sum[3] = {0.f, 0.f, 0.f};
    for (int i = tid; i < B; i += 1024) {
        sum[0] += expf(z2[3 * i + 0] - M[0]);
        sum[1] += expf(z2[3 * i + 1] - M[1]);
        sum[2] += expf(z2[3 * i + 2] - M[2]);
    }
    for (int c = 0; c < 3; c++) red[c][tid] = sum[c];
    __syncthreads();
    for (int s = 512; s > 0; s >>= 1) {
        if (tid < s)
            for (int c = 0; c < 3; c++) red[c][tid] += red[c][tid + s];
        __syncthreads();
    }
    if (tid == 0)
        for (int c = 0; c < 3; c++) { stats[c] = M[c]; stats[3 + c] = logf(red[c][0]); }
}

__global__ void k_final(const float* __restrict__ z2, const float* __restrict__ stats,
                        float* __restrict__ out, int n) {
    int i = blockIdx.x * blockDim.x + threadIdx.x;
    if (i < n) {
        int c = i % 3;
        out[i] = z2[i] - stats[c] - stats[3 + c];
    }
}

// ---- launch --------------------------------------------------------------

extern "C" void kernel_launch(void* const* d_in, const int* in_sizes, int n_in,
                              void* d_out, int out_size, void* d_ws, size_t ws_size,
                              hipStream_t stream) {
    const int*   edge_index = (const int*)d_in[0];
    const int*   src  = edge_index;
    const int*   dst  = edge_index + N_EDGES;
    const float* ew   = (const float*)d_in[1];
    const int*   home = (const int*)d_in[2];
    const int*   away = (const int*)d_in[3];
    const float* emb  = (const float*)d_in[4];
    const float* W0 = (const float*)d_in[5];  const float* b0 = (const float*)d_in[6];
    const float* W1 = (const float*)d_in[7];  const float* b1 = (const float*)d_in[8];
    const float* W2 = (const float*)d_in[9];  const float* b2 = (const float*)d_in[10];
    const float* l1W = (const float*)d_in[11]; const float* l1b = (const float*)d_in[12];
    const float* l3W = (const float*)d_in[13]; const float* l3b = (const float*)d_in[14];

    char* p = (char*)d_ws;
    float*          dinv      = (float*)p;          p += NPAD * 4;
    int*            cnt       = (int*)p;            p += NPAD * 4;
    int*            fill      = (int*)p;            p += NPAD * 4;
    int*            row_start = (int*)p;            p += (NPAD + 1024) * 4;
    int*            partial   = (int*)p;            p += 128 * 4;
    int2*           edges     = (int2*)p;           p += (size_t)N_EDGES * 8;
    unsigned short* xbA       = (unsigned short*)p; p += (size_t)N_TEAMS * 64 * 2;
    unsigned short* xbB       = (unsigned short*)p; p += (size_t)N_TEAMS * 64 * 2;
    float*          z2        = (float*)p;          p += (size_t)BATCH * 3 * 4;
    float*          stats     = (float*)p;

    const int scanBlocks = NPAD / 1024;  // 98

    // ---- CSR build (once, reused by all 3 layers) ----
    k_zero<<<NPAD / 256, 256, 0, stream>>>(cnt, NPAD);
    k_cnt<<<(N_EDGES + 255) / 256, 256, 0, stream>>>(dst, cnt, N_EDGES);
    k_scan1<<<scanBlocks, 1024, 0, stream>>>(cnt, row_start, partial, N_TEAMS);
    k_scan2<<<1, 128, 0, stream>>>(partial, scanBlocks);
    k_scan3<<<scanBlocks, 1024, 0, stream>>>(row_start, fill, partial);
    k_bucket<<<(N_EDGES + 255) / 256, 256, 0, stream>>>(src, dst, ew, fill, edges, N_EDGES);
    k_dinv<<<(N_TEAMS + 255) / 256, 256, 0, stream>>>(row_start, (const int*)edges, dinv, N_TEAMS);
    k_cvt<<<(N_TEAMS * 16 + 255) / 256, 256, 0, stream>>>(emb, dinv, xbA, N_TEAMS * 16);

    const int LBLOCKS = 2048;            // persistent: 8 blocks/CU
    const int LWAVES  = LBLOCKS * 4;
    const int NPAIRS  = N_TEAMS / 2;     // 50000

    // layer 0..2 fused: agg + GEMM + bias + leaky (+ dinv pre-scale for next)
    k_layer<<<LBLOCKS, 256, 0, stream>>>(xbA, row_start, (const long long*)edges, dinv,
                                         W0, b0, xbB, NPAIRS, LWAVES, 1);
    k_layer<<<LBLOCKS, 256, 0, stream>>>(xbB, row_start, (const long long*)edges, dinv,
                                         W1, b1, xbA, NPAIRS, LWAVES, 1);
    k_layer<<<LBLOCKS, 256, 0, stream>>>(xbA, row_start, (const long long*)edges, dinv,
                                         W2, b2, xbB, NPAIRS, LWAVES, 0);

    // head + column log-softmax
    k_head<<<(BATCH + 255) / 256, 256, 0, stream>>>(xbB, home, away, l1W, l1b, l3W, l3b, z2, BATCH);
    k_stats<<<1, 1024, 0, stream>>>(z2, stats, BATCH);
    k_final<<<(BATCH * 3 + 255) / 256, 256, 0, stream>>>(z2, stats, (float*)d_out, BATCH * 3);
}